// Round 15
// baseline (121.926 us; speedup 1.0000x reference)
//
#include <hip/hip_runtime.h>
#include <hip/hip_fp16.h>

#define NW 20

typedef _Float16 h2 __attribute__((ext_vector_type(2)));
typedef float    f4 __attribute__((ext_vector_type(4)));

// splat coefficient set for one wire's fused RY*RX unitary
// U = [[a+id, -e-if],[e-if, a-id]]
struct PkW7 { h2 a, d, dn, e, en, f, fn, pad; };   // 32 B

__device__ __forceinline__ h2 pkrtz(float lo, float hi) {
    typedef __fp16 f16x2 __attribute__((ext_vector_type(2)));
    f16x2 v = __builtin_amdgcn_cvt_pkrtz(lo, hi);
    return *reinterpret_cast<h2*>(&v);
}
__device__ __forceinline__ unsigned h2u(h2 v) { return *reinterpret_cast<unsigned*>(&v); }
__device__ __forceinline__ h2 u2h(unsigned v) { return *reinterpret_cast<h2*>(&v); }

// async global->LDS, 16B per lane (wave-uniform LDS base + lane*16 in HW)
__device__ __forceinline__ void glds16(const float* g, float* l) {
    __builtin_amdgcn_global_load_lds(
        (const __attribute__((address_space(1))) void*)g,
        (__attribute__((address_space(3))) void*)l, 16, 0, 0);
}
// pure-LDS barrier: does NOT drain vmcnt -> in-flight global_load_lds survives
__device__ __forceinline__ void lds_barrier() {
    asm volatile("s_waitcnt lgkmcnt(0)" ::: "memory");
    __builtin_amdgcn_s_barrier();
}

// SoA packed butterfly: re/im in separate v2f16, each = 2 batch states.
template<int JB>
__device__ __forceinline__ void stage16s(h2 (&xr)[16], h2 (&xi)[16], const PkW7 u) {
    #pragma unroll
    for (int base = 0; base < 16; ++base)
        if (!(base & (1 << JB))) {
            const int p = base | (1 << JB);
            h2 x0r = xr[base], x0i = xi[base], x1r = xr[p], x1i = xi[p];
            xr[base] = u.a * x0r + u.dn * x0i + u.en * x1r + u.f  * x1i;
            xi[base] = u.a * x0i + u.d  * x0r + u.en * x1i + u.fn * x1r;
            xr[p]    = u.e * x0r + u.f  * x0i + u.a  * x1r + u.d  * x1i;
            xi[p]    = u.e * x0i + u.fn * x0r + u.a  * x1i + u.dn * x1r;
        }
}

// Shuffle butterfly stage on lane-bit JB (amp-bit 2+JB).
template<int JB>
__device__ __forceinline__ void shufstage(h2 (&xr)[16], h2 (&xi)[16], const PkW7 u, int t) {
    const bool hi_ = (t >> JB) & 1;
    const h2 ds_  = hi_ ? u.d  : u.dn;
    const h2 nds_ = hi_ ? u.dn : u.d;
    const h2 es_  = hi_ ? u.e  : u.en;
    #pragma unroll
    for (int r = 0; r < 16; ++r) {
        h2 or_ = xr[r], oi_ = xi[r];
        int pri = __shfl_xor(*reinterpret_cast<int*>(&or_), 1 << JB, 64);
        int pii = __shfl_xor(*reinterpret_cast<int*>(&oi_), 1 << JB, 64);
        h2 pr_ = *reinterpret_cast<h2*>(&pri);
        h2 pi_ = *reinterpret_cast<h2*>(&pii);
        xr[r] = u.a * or_ + ds_  * oi_ + es_ * pr_ + u.f  * pi_;
        xi[r] = u.a * oi_ + nds_ * or_ + es_ * pi_ + u.fn * pr_;
    }
}

// cbuf layout: [0..3] = wire19 f32 (a,d,e,f)*1024 ; then PkW7[20] at cbuf+4
__global__ void setupk(const float* __restrict__ params, float* __restrict__ cbuf) {
    int w = threadIdx.x;
    if (w < NW) {
        double s1, c1, s2, c2;
        sincos(0.5 * (double)params[w],      &s1, &c1);   // RX
        sincos(0.5 * (double)params[w + NW], &s2, &c2);   // RY
        float a = (float)(c1 * c2), d = (float)(s1 * s2);
        float e = (float)(s2 * c1), f = (float)(c2 * s1);
        if (w == 19) {
            cbuf[0] = a * 1024.f; cbuf[1] = d * 1024.f;
            cbuf[2] = e * 1024.f; cbuf[3] = f * 1024.f;
        }
        PkW7 pw;
        pw.a.x  = (_Float16) a; pw.a.y  = (_Float16) a;
        pw.d.x  = (_Float16) d; pw.d.y  = (_Float16) d;
        pw.dn.x = (_Float16)-d; pw.dn.y = (_Float16)-d;
        pw.e.x  = (_Float16) e; pw.e.y  = (_Float16) e;
        pw.en.x = (_Float16)-e; pw.en.y = (_Float16)-e;
        pw.f.x  = (_Float16) f; pw.f.y  = (_Float16) f;
        pw.fn.x = (_Float16)-f; pw.fn.y = (_Float16)-f;
        pw.pad.x = (_Float16)0.f; pw.pad.y = (_Float16)0.f;
        ((PkW7*)(cbuf + 4))[w] = pw;
    }
}

// ---------------------------------------------------------------------------
// Pass 1 v3: persistent 2-chunk pipeline with async LDS staging.
// Block = (pr, gg); chunks c_j = gg + 128*j, j=0..1. While chunk j is
// computed (from regs), chunk j+1 streams into LDS staging via
// global_load_lds. Exchange barriers are raw lgkmcnt-only so the prefetch
// stays in flight. SMEM: staging 8192 f32 (32KB) + exch 4224 h2 (16.9KB).
// ---------------------------------------------------------------------------
__global__ __launch_bounds__(256, 3) void pass1(const float* __restrict__ state,
                                                const float* __restrict__ cbuf,
                                                uint2* __restrict__ amp) {
    __shared__ float SMEM[8192 + 4224];
    float* stg = SMEM;                      // 32 KB staging
    h2*    L   = reinterpret_cast<h2*>(SMEM + 8192);   // 16.9 KB exchange
    const int t  = threadIdx.x;
    const int pr = blockIdx.x >> 7;         // batch pair (pr, pr+16)
    const int gg = blockIdx.x & 127;
    const PkW7* PW = (const PkW7*)(cbuf + 4);
    const float a19 = cbuf[0], d19 = cbuf[1], e19 = cbuf[2], f19 = cbuf[3];

    const float* base0 = state + ((size_t)pr << 20);
    const float* base1 = base0 + ((size_t)16 << 20);
    const int w  = t >> 6, ln = t & 63;

    // issue staging for chunk c_0: 8 wave-instrs/wave; sg = m*4+w in [0,32)
    {
        const float* c0b0 = base0 + ((size_t)gg << 12);
        const float* c0b1 = base1 + ((size_t)gg << 12);
        #pragma unroll
        for (int m = 0; m < 8; ++m) {
            const int sg = m * 4 + w;
            const int off = ((sg & 15) << 8) + (ln << 2);
            glds16((sg < 16 ? c0b0 : c0b1) + off, &stg[(sg << 8) + (ln << 2)]);
        }
    }

    #pragma unroll
    for (int j = 0; j < 2; ++j) {
        const int c = gg + 128 * j;
        // wait staged chunk c, all waves
        asm volatile("s_waitcnt vmcnt(0)" ::: "memory");
        __builtin_amdgcn_s_barrier();

        // staging -> regs (8 x ds_read_b128)
        f4 va[4], vb[4];
        #pragma unroll
        for (int k = 0; k < 4; ++k) {
            va[k] = *reinterpret_cast<const f4*>(&stg[k * 1024 + 4 * t]);
            vb[k] = *reinterpret_cast<const f4*>(&stg[4096 + k * 1024 + 4 * t]);
        }
        lds_barrier();                      // staging free

        if (j == 0) {                       // prefetch chunk c_1 (async)
            const float* c1b0 = base0 + ((size_t)(gg + 128) << 12);
            const float* c1b1 = base1 + ((size_t)(gg + 128) << 12);
            #pragma unroll
            for (int m = 0; m < 8; ++m) {
                const int sg = m * 4 + w;
                const int off = ((sg & 15) << 8) + (ln << 2);
                glds16((sg < 16 ? c1b0 : c1b1) + off, &stg[(sg << 8) + (ln << 2)]);
            }
        }

        // Round 1: i = (r&3) + 4t + 1024(r>>2); bits {0,1,10,11} -> 19(f32),18,9,8
        h2 xr[16], xi[16];
        #pragma unroll
        for (int k = 0; k < 4; ++k) {
            f4 v0 = va[k], v1 = vb[k];
            float r0a = fmaf(a19, v0.x, -e19 * v0.y), i0a = fmaf( d19, v0.x, -f19 * v0.y);
            float r1a = fmaf(e19, v0.x,  a19 * v0.y), i1a = fmaf(-f19, v0.x, -d19 * v0.y);
            float r0b = fmaf(a19, v1.x, -e19 * v1.y), i0b = fmaf( d19, v1.x, -f19 * v1.y);
            float r1b = fmaf(e19, v1.x,  a19 * v1.y), i1b = fmaf(-f19, v1.x, -d19 * v1.y);
            xr[4*k+0] = pkrtz(r0a, r0b); xi[4*k+0] = pkrtz(i0a, i0b);
            xr[4*k+1] = pkrtz(r1a, r1b); xi[4*k+1] = pkrtz(i1a, i1b);
            r0a = fmaf(a19, v0.z, -e19 * v0.w); i0a = fmaf( d19, v0.z, -f19 * v0.w);
            r1a = fmaf(e19, v0.z,  a19 * v0.w); i1a = fmaf(-f19, v0.z, -d19 * v0.w);
            r0b = fmaf(a19, v1.z, -e19 * v1.w); i0b = fmaf( d19, v1.z, -f19 * v1.w);
            r1b = fmaf(e19, v1.z,  a19 * v1.w); i1b = fmaf(-f19, v1.z, -d19 * v1.w);
            xr[4*k+2] = pkrtz(r0a, r0b); xi[4*k+2] = pkrtz(i0a, i0b);
            xr[4*k+3] = pkrtz(r1a, r1b); xi[4*k+3] = pkrtz(i1a, i1b);
        }
        stage16s<1>(xr, xi, PW[18]);        // i-bit 1  -> wire 18
        stage16s<2>(xr, xi, PW[9]);         // i-bit 10 -> wire 9
        stage16s<3>(xr, xi, PW[8]);         // i-bit 11 -> wire 8

        // shfl stages: i-bits 2..5 (lane bits 0..3) -> wires 17..14
        shufstage<0>(xr, xi, PW[17], t);
        shufstage<1>(xr, xi, PW[16], t);
        shufstage<2>(xr, xi, PW[15], t);
        shufstage<3>(xr, xi, PW[14], t);

        // ONE exchange (raw lds barriers; glds prefetch stays in flight):
        // write SK(i): p1 + (r&3) + 1056(r>>2), p1 = 4t + (t>>3)
        // read  SK(i'): q + 66(r&3) + 264(r>>2),
        //   i' = (t&63) + 64(r&3) + 256(r>>2) + 1024(t>>6)
        const int p1 = 4 * t + (t >> 3);
        const int q  = (t & 63) + ((t & 63) >> 5) + 1056 * (t >> 6);
        #pragma unroll
        for (int r = 0; r < 16; ++r) L[p1 + (r & 3) + 1056 * (r >> 2)] = xr[r];
        lds_barrier();
        #pragma unroll
        for (int r = 0; r < 16; ++r) xr[r] = L[q + 66 * (r & 3) + 264 * (r >> 2)];
        lds_barrier();
        #pragma unroll
        for (int r = 0; r < 16; ++r) L[p1 + (r & 3) + 1056 * (r >> 2)] = xi[r];
        lds_barrier();
        #pragma unroll
        for (int r = 0; r < 16; ++r) xi[r] = L[q + 66 * (r & 3) + 264 * (r >> 2)];

        // post-exchange reg stages: i'-bits {6,7} -> wires 13,12 ; {8,9} -> 11,10
        stage16s<0>(xr, xi, PW[13]);
        stage16s<1>(xr, xi, PW[12]);
        stage16s<2>(xr, xi, PW[11]);
        stage16s<3>(xr, xi, PW[10]);

        // store: i' layout, 512B/wave contiguous
        uint2* dst = amp + ((size_t)pr << 20) + ((size_t)c << 12);
        const int sb = (t & 63) + 1024 * (t >> 6);
        #pragma unroll
        for (int r = 0; r < 16; ++r) {
            uint2 wv; wv.x = h2u(xr[r]); wv.y = h2u(xi[r]);
            dst[sb + 64 * (r & 3) + 256 * (r >> 2)] = wv;
        }
        // next loop-top barrier orders store completion + staging reuse
        if (j == 0) lds_barrier();          // ensure exch reads done before... (uniform)
    }
}

// ---------------------------------------------------------------------------
// Pass 2: wires 0..7 (y bits 12..19) — unchanged from R13/R14 (~13 us).
// ---------------------------------------------------------------------------
__global__ __launch_bounds__(256, 8) void pass2(const uint2* __restrict__ amp,
                                                const float* __restrict__ cbuf,
                                                const float* __restrict__ Wv,
                                                float* __restrict__ pws) {
    __shared__ h2     L[4224];
    __shared__ float2 Asig[256];
    __shared__ float  Btab[16];
    __shared__ float  wred[8];
    const int t        = threadIdx.x;
    const int pr       = blockIdx.x >> 8;
    const int chunk    = blockIdx.x & 255;
    const int low_base = chunk * 16;
    const int l = t & 15, hi = t >> 4;
    const PkW7* PW = (const PkW7*)(cbuf + 4);

    {
        float A = 0.f;
        #pragma unroll
        for (int i = 0; i < 8; ++i)
            A += Wv[i] * (1.f - 2.f * (float)(__popc(t >> (7 - i)) & 1));
        Asig[t] = make_float2(A, 1.f - 2.f * (float)(__popc(t) & 1));
    }
    if (t < 16) {
        int low = low_base + t;
        float Bs = 0.f;
        #pragma unroll
        for (int i = 8; i < 20; ++i)
            Bs += Wv[i] * (1.f - 2.f * (float)(__popc(low >> (19 - i)) & 1));
        Btab[t] = Bs;
    }

    const uint2* src = amp + ((size_t)pr << 20) + low_base + l;
    h2 xr[16], xi[16];
    #pragma unroll
    for (int r = 0; r < 16; ++r) {
        uint2 w = src[(size_t)(hi * 16 + r) * 4096];
        xr[r] = u2h(w.x); xi[r] = u2h(w.y);
    }
    stage16s<0>(xr, xi, PW[7]);
    stage16s<1>(xr, xi, PW[6]);
    stage16s<2>(xr, xi, PW[5]);
    stage16s<3>(xr, xi, PW[4]);

    const int p = 264 * hi + l;
    const int q = t + (t >> 5);
    #pragma unroll
    for (int r = 0; r < 16; ++r) L[p + 16 * r + (r >> 1)] = xr[r];
    __syncthreads();
    #pragma unroll
    for (int r = 0; r < 16; ++r) xr[r] = L[q + 264 * r];
    __syncthreads();
    #pragma unroll
    for (int r = 0; r < 16; ++r) L[p + 16 * r + (r >> 1)] = xi[r];
    __syncthreads();
    #pragma unroll
    for (int r = 0; r < 16; ++r) xi[r] = L[q + 264 * r];

    stage16s<0>(xr, xi, PW[3]);
    stage16s<1>(xr, xi, PW[2]);
    stage16s<2>(xr, xi, PW[1]);
    stage16s<3>(xr, xi, PW[0]);

    const float Bl = Btab[l];
    float acc0 = 0.f, acc1 = 0.f;
    #pragma unroll
    for (int r = 0; r < 16; ++r) {
        float vrx = (float)xr[r].x, vry = (float)xr[r].y;
        float vix = (float)xi[r].x, viy = (float)xi[r].y;
        float2 as = Asig[r * 16 + hi];
        float g = fmaf(as.y, Bl, as.x);
        acc0 = fmaf(fmaf(vrx, vrx, vix * vix), g, acc0);
        acc1 = fmaf(fmaf(vry, vry, viy * viy), g, acc1);
    }
    #pragma unroll
    for (int off = 32; off > 0; off >>= 1) {
        acc0 += __shfl_down(acc0, off, 64);
        acc1 += __shfl_down(acc1, off, 64);
    }
    if ((t & 63) == 0) { wred[(t >> 6) * 2] = acc0; wred[(t >> 6) * 2 + 1] = acc1; }
    __syncthreads();
    if (t < 2)
        pws[blockIdx.x * 2 + t] = (wred[t] + wred[2 + t]) + (wred[4 + t] + wred[6 + t]);
}

// ---------------------------------------------------------------------------
// Final: deterministic reduction of 256 partials per batch, undo 2^20 scale.
// ---------------------------------------------------------------------------
__global__ void finalk(const float* __restrict__ pws, const float* __restrict__ bias,
                       float* __restrict__ out) {
    const int t = threadIdx.x;
    const int b = t >> 3, j = t & 7;
    const int pr = b & 15, sl = b >> 4;
    float s = 0.f;
    #pragma unroll 4
    for (int k = 0; k < 32; ++k) {
        const int c = j * 32 + k;
        s += pws[(pr * 256 + c) * 2 + sl];
    }
    s += __shfl_down(s, 4, 8);
    s += __shfl_down(s, 2, 8);
    s += __shfl_down(s, 1, 8);
    if (j == 0) out[b] = s * (1.f / 1048576.f) + bias[0];
}

extern "C" void kernel_launch(void* const* d_in, const int* in_sizes, int n_in,
                              void* d_out, int out_size, void* d_ws, size_t ws_size,
                              hipStream_t stream) {
    const float* state  = (const float*)d_in[0];   // (32, 2^20) f32
    const float* params = (const float*)d_in[1];   // (40,) f32
    const float* Wv     = (const float*)d_in[2];   // (1,20) f32
    const float* bias   = (const float*)d_in[3];   // (1,)  f32
    float* out = (float*)d_out;                    // (32,) f32

    const size_t AMPB = (size_t)16 * (1u << 20) * 8;   // 128 MiB intermediate
    uint2* amp  = (uint2*)d_ws;
    float* pws  = (float*)((char*)d_ws + AMPB);
    float* cbuf = (float*)((char*)d_ws + AMPB + 65536);

    setupk<<<1, 64, 0, stream>>>(params, cbuf);
    pass1 <<<16 * 128, 256, 0, stream>>>(state, cbuf, amp);
    pass2 <<<16 * 256, 256, 0, stream>>>(amp, cbuf, Wv, pws);
    finalk<<<1, 256, 0, stream>>>(pws, bias, out);
}